// Round 10
// baseline (180.369 us; speedup 1.0000x reference)
//
#include <hip/hip_runtime.h>
#include <hip/hip_cooperative_groups.h>
#include <hip/hip_bf16.h>
#include <stdint.h>

namespace cg = cooperative_groups;

// Problem constants (B,S,D,K) = (2,4096,512,32)
#define S_LEN  4096
#define D_DIM  512
#define K_R    32
#define M_ROWS 8192

typedef __attribute__((ext_vector_type(8))) short bf16x8;
typedef __attribute__((ext_vector_type(4))) float f32x4;

__device__ __forceinline__ float bf2f(short u) {
  union { unsigned int i; float f; } c;
  c.i = ((unsigned int)(unsigned short)u) << 16;
  return c.f;
}

__device__ __forceinline__ void gload_lds16(const void* g, void* lds) {
  __builtin_amdgcn_global_load_lds(
      (__attribute__((address_space(1))) void*)g,
      (__attribute__((address_space(3))) void*)lds, 16, 0, 0);
}

__device__ __forceinline__ int4 pack8(float4 v0, float4 v1) {
  union { __hip_bfloat16 h[8]; int4 v; } u;
  u.h[0] = __float2bfloat16(v0.x); u.h[1] = __float2bfloat16(v0.y);
  u.h[2] = __float2bfloat16(v0.z); u.h[3] = __float2bfloat16(v0.w);
  u.h[4] = __float2bfloat16(v1.x); u.h[5] = __float2bfloat16(v1.y);
  u.h[6] = __float2bfloat16(v1.z); u.h[7] = __float2bfloat16(v1.w);
  return u.v;
}

// ---------------------------------------------------------------------------
// Kernel 1 (prep_w): weights only. blocks [0,64): cast W_in -> Winb.
//                    blocks [64,128): transpose-cast W_out -> WoutTb.
//   (R4-proven code paths.)
// ---------------------------------------------------------------------------
__global__ void __launch_bounds__(256) prep_w_kernel(
    const float* __restrict__ Win, __hip_bfloat16* __restrict__ Winb,
    const float* __restrict__ Wout, __hip_bfloat16* __restrict__ WoutTb) {
  __shared__ __hip_bfloat16 Lds[64][66];
  const int tid = threadIdx.x;
  if (blockIdx.x < 64) {
    const int e4 = (blockIdx.x * 256 + tid) * 4;
    const float4* wp = (const float4*)Win;
    int4* op = (int4*)Winb;
#pragma unroll
    for (int h = 0; h < 2; ++h)
      op[e4 / 2 + h] = pack8(wp[e4 + 2 * h], wp[e4 + 2 * h + 1]);
    return;
  }
  const int bx = blockIdx.x - 64;
  const int tr = (bx >> 3) * 64;
  const int tc = (bx & 7) * 64;
#pragma unroll
  for (int it = 0; it < 4; ++it) {
    const int id = it * 256 + tid;
    const int r = id >> 4, c4 = (id & 15) * 4;
    const float4 v = *(const float4*)&Wout[(size_t)(tr + r) * 512 + tc + c4];
    Lds[r][c4]     = __float2bfloat16(v.x);
    Lds[r][c4 + 1] = __float2bfloat16(v.y);
    Lds[r][c4 + 2] = __float2bfloat16(v.z);
    Lds[r][c4 + 3] = __float2bfloat16(v.w);
  }
  __syncthreads();
#pragma unroll
  for (int it = 0; it < 2; ++it) {
    const int id = it * 256 + tid;
    const int j = id >> 3, i0 = (id & 7) * 8;
    union { __hip_bfloat16 h[8]; int4 v; } u;
#pragma unroll
    for (int r = 0; r < 8; ++r) u.h[r] = Lds[i0 + r][j];
    *(int4*)&WoutTb[(size_t)(tc + j) * 512 + tr + i0] = u.v;
  }
}

// ---------------------------------------------------------------------------
// Kernel 2 (mega, cooperative, 512 blocks x 256 thr, 2 blocks/CU):
//   Phase 0: all blocks cast 16 x-rows (rows id2*16..+16); blocks 0..63 also
//            compute one 64x64 WcT tile (swizzled MFMA, proven pattern).
//   sync -> Phase A: each block gathers its 16 rows -> g (shfl-broadcast w/r).
//   sync -> Phase B: R9 3-deep counted-vmcnt gemm: out = x + g@Wc + b_out.
// ---------------------------------------------------------------------------
__global__ void __launch_bounds__(256, 2) mega_kernel(
    const float* __restrict__ x,
    __hip_bfloat16* __restrict__ Xb,
    const __hip_bfloat16* __restrict__ Winb,
    const __hip_bfloat16* __restrict__ WoutTb,
    __hip_bfloat16* __restrict__ WcT,
    __hip_bfloat16* __restrict__ g,
    const float* __restrict__ b_out,
    const float* __restrict__ fw,
    const int* __restrict__ routes,
    float* __restrict__ out) {
  union SMem {
    struct { ushort A[3 * 128 * 64]; ushort B[3 * 64 * 64]; } g3;  // 72 KB
    struct { ushort A[64 * 64]; ushort B[64 * 64]; } wc;           // 16 KB
  };
  __shared__ SMem sm;
  cg::grid_group grid = cg::this_grid();
  const int tid = threadIdx.x;
  const int bid = blockIdx.x;
  const int w = tid >> 6, l = tid & 63;
  const int id2 = (bid & 7) * 64 + (bid >> 3);   // XCD-chunked identity
  const int fr = l & 15, fq = l >> 4;

  // ---------------- Phase 0: x-cast (all blocks, 16 rows each) ------------
  {
    const int r0 = id2 * 16;
#pragma unroll
    for (int it = 0; it < 4; ++it) {
      const int idx = it * 256 + tid;            // [0,1024)
      const int row = r0 + (idx >> 6), u8 = idx & 63;
      const float4* px = (const float4*)(x + (size_t)row * 512 + u8 * 8);
      ((int4*)(Xb + (size_t)row * 512))[u8] = pack8(px[0], px[1]);
    }
  }
  // ---------------- Phase 0b: wcgemm 64x64 tiles on blocks 0..63 ----------
  if (bid < 64) {
    const int tj = (bid >> 3) * 64, tq = (bid & 7) * 64;
    const int rin = l >> 3, usw = (l & 7) ^ rin;
    const int wr = (w >> 1) * 32, wq = (w & 1) * 32;
    f32x4 acc[2][2] = {};
    for (int k0 = 0; k0 < 512; k0 += 64) {
      __syncthreads();
#pragma unroll
      for (int i = 0; i < 2; ++i) {
        gload_lds16(WoutTb + (size_t)(tj + w * 8 + i * 32 + rin) * 512 + k0 + usw * 8,
                    sm.wc.A + (w * 8 + i * 32) * 64);
        gload_lds16(Winb + (size_t)(tq + w * 8 + i * 32 + rin) * 512 + k0 + usw * 8,
                    sm.wc.B + (w * 8 + i * 32) * 64);
      }
      __syncthreads();
#pragma unroll
      for (int kk = 0; kk < 2; ++kk) {
        const int u = (kk * 4 + fq) ^ (fr & 7);
        bf16x8 af[2], bfv[2];
#pragma unroll
        for (int m = 0; m < 2; ++m)
          af[m] = *(const bf16x8*)(sm.wc.A + (wr + m * 16 + fr) * 64 + u * 8);
#pragma unroll
        for (int n = 0; n < 2; ++n)
          bfv[n] = *(const bf16x8*)(sm.wc.B + (wq + n * 16 + fr) * 64 + u * 8);
#pragma unroll
        for (int m = 0; m < 2; ++m)
#pragma unroll
          for (int n = 0; n < 2; ++n)
            acc[m][n] = __builtin_amdgcn_mfma_f32_16x16x32_bf16(af[m], bfv[n], acc[m][n], 0, 0, 0);
      }
    }
#pragma unroll
    for (int m = 0; m < 2; ++m)
#pragma unroll
      for (int n = 0; n < 2; ++n)
#pragma unroll
        for (int r = 0; r < 4; ++r)
          WcT[(size_t)(tj + wr + m * 16 + fq * 4 + r) * 512 + tq + wq + n * 16 + fr] =
              __float2bfloat16(acc[m][n][r]);
  }
  grid.sync();

  // ---------------- Phase A: gather 16 rows/block -------------------------
  {
    const int r0 = id2 * 16;
#pragma unroll
    for (int rr = 0; rr < 4; ++rr) {
      const int row = r0 + w * 4 + rr;
      const int s = row & (S_LEN - 1);
      const int b = row >> 12;
      int rt_l = 0; float wk_l = 0.f;
      if (l < K_R) {
        rt_l = routes[s * K_R + l];
        wk_l = fw[s * K_R + l];
      }
      const __hip_bfloat16* xbb = Xb + (size_t)b * S_LEN * D_DIM + l * 8;
      float acc[8] = {};
#pragma unroll 8
      for (int k = 0; k < K_R; ++k) {
        const int rt = __shfl(rt_l, k);
        const float wk = __shfl(wk_l, k);
        const bf16x8 v = *(const bf16x8*)(xbb + (size_t)rt * D_DIM);
#pragma unroll
        for (int j = 0; j < 8; ++j) acc[j] = fmaf(wk, bf2f(v[j]), acc[j]);
      }
      union { __hip_bfloat16 h[8]; int4 v; } u;
#pragma unroll
      for (int j = 0; j < 8; ++j) u.h[j] = __float2bfloat16(acc[j]);
      *(int4*)(g + (size_t)row * D_DIM + l * 8) = u.v;
    }
  }
  grid.sync();

  // ---------------- Phase B: out = x + g @ Wc + b_out (R9 pipeline) -------
  {
    const int bm0 = (id2 >> 3) * 128;
    const int bn0 = (id2 & 7) * 64;
    const int wr  = (w >> 1) * 64;
    const int wcn = (w & 1) * 32;
    const int rin = l >> 3;
    const int usw = (l & 7) ^ rin;
    const __hip_bfloat16* gA = g + (size_t)(bm0 + w * 8 + rin) * D_DIM + usw * 8;
    const __hip_bfloat16* gB = WcT + (size_t)(bn0 + w * 8 + rin) * D_DIM + usw * 8;
    ushort* AsU = sm.g3.A;
    ushort* BsU = sm.g3.B;
    f32x4 acc[4][2] = {};

#define STAGE(buf, k0)                                                          \
  {                                                                             \
    _Pragma("unroll")                                                           \
    for (int i = 0; i < 4; ++i)                                                 \
      gload_lds16(gA + (size_t)(i * 32) * D_DIM + (k0),                         \
                  AsU + (buf) * 8192 + (w * 8 + i * 32) * 64);                  \
    _Pragma("unroll")                                                           \
    for (int j = 0; j < 2; ++j)                                                 \
      gload_lds16(gB + (size_t)(j * 32) * D_DIM + (k0),                         \
                  BsU + (buf) * 4096 + (w * 8 + j * 32) * 64);                  \
  }

#define COMPUTE(buf)                                                            \
  {                                                                             \
    _Pragma("unroll")                                                           \
    for (int kk = 0; kk < 2; ++kk) {                                            \
      const int u = (kk * 4 + fq) ^ (fr & 7);                                   \
      bf16x8 af[4], bfv[2];                                                     \
      _Pragma("unroll")                                                         \
      for (int m = 0; m < 4; ++m)                                               \
        af[m] = *(const bf16x8*)(AsU + (buf) * 8192 + (wr + m * 16 + fr) * 64 + u * 8); \
      _Pragma("unroll")                                                         \
      for (int n = 0; n < 2; ++n)                                               \
        bfv[n] = *(const bf16x8*)(BsU + (buf) * 4096 + (wcn + n * 16 + fr) * 64 + u * 8); \
      _Pragma("unroll")                                                         \
      for (int m = 0; m < 4; ++m)                                               \
        _Pragma("unroll")                                                       \
        for (int n = 0; n < 2; ++n)                                             \
          acc[m][n] = __builtin_amdgcn_mfma_f32_16x16x32_bf16(                  \
              af[m], bfv[n], acc[m][n], 0, 0, 0);                               \
    }                                                                           \
  }

    STAGE(0, 0);
    STAGE(1, 64);
#pragma unroll
    for (int t = 0; t < 7; ++t) {
      asm volatile("s_waitcnt vmcnt(6)" ::: "memory");
      __builtin_amdgcn_s_barrier();
      __builtin_amdgcn_sched_barrier(0);
      if (t < 6) STAGE((t + 2) % 3, (t + 2) * 64);
      COMPUTE(t % 3);
    }
    asm volatile("s_waitcnt vmcnt(0)" ::: "memory");
    __builtin_amdgcn_s_barrier();
    __builtin_amdgcn_sched_barrier(0);
    COMPUTE(1);   // 7 % 3
#undef STAGE
#undef COMPUTE

    const float bb0 = b_out[bn0 + wcn + fr];
    const float bb1 = b_out[bn0 + wcn + 16 + fr];
#pragma unroll
    for (int m = 0; m < 4; ++m)
#pragma unroll
      for (int r = 0; r < 4; ++r) {
        const int grow = bm0 + wr + m * 16 + fq * 4 + r;
        const size_t base = (size_t)grow * D_DIM + bn0 + wcn + fr;
        out[base]      = acc[m][0][r] + x[base]      + bb0;
        out[base + 16] = acc[m][1][r] + x[base + 16] + bb1;
      }
  }
}

// ---------------------------------------------------------------------------
extern "C" void kernel_launch(void* const* d_in, const int* in_sizes, int n_in,
                              void* d_out, int out_size, void* d_ws, size_t ws_size,
                              hipStream_t stream) {
  const float* x      = (const float*)d_in[0];
  const float* W_in   = (const float*)d_in[1];
  const float* W_out  = (const float*)d_in[2];
  const float* b_out  = (const float*)d_in[3];
  const float* fw     = (const float*)d_in[4];
  const int*   routes = (const int*)d_in[5];
  float* out = (float*)d_out;

  // workspace: Xb(8MB) | WcT(512KB) | g(8MB) | Winb(512KB) | WoutTb(512KB)
  char* ws = (char*)d_ws;
  __hip_bfloat16* Xb     = (__hip_bfloat16*)ws;
  __hip_bfloat16* WcT    = (__hip_bfloat16*)(ws + 8388608);
  __hip_bfloat16* g      = (__hip_bfloat16*)(ws + 8912896);
  __hip_bfloat16* Winb   = (__hip_bfloat16*)(ws + 17301504);
  __hip_bfloat16* WoutTb = (__hip_bfloat16*)(ws + 17825792);

  // 1) weight casts + transpose (small)
  prep_w_kernel<<<128, 256, 0, stream>>>(W_in, Winb, W_out, WoutTb);

  // 2) cooperative mega-kernel: cast+wc | sync | gather | sync | gemm
  void* args[10];
  args[0] = (void*)&x;      args[1] = (void*)&Xb;
  args[2] = (void*)&Winb;   args[3] = (void*)&WoutTb;
  args[4] = (void*)&WcT;    args[5] = (void*)&g;
  args[6] = (void*)&b_out;  args[7] = (void*)&fw;
  args[8] = (void*)&routes; args[9] = (void*)&out;
  hipLaunchCooperativeKernel((const void*)mega_kernel, dim3(512), dim3(256),
                             args, 0, stream);
}

// Round 11
// 145.869 us; speedup vs baseline: 1.2365x; 1.2365x over previous
//
#include <hip/hip_runtime.h>
#include <hip/hip_bf16.h>
#include <stdint.h>

// Problem constants (B,S,D,K) = (2,4096,512,32)
#define S_LEN  4096
#define D_DIM  512
#define K_R    32
#define M_ROWS 8192

typedef __attribute__((ext_vector_type(8))) short bf16x8;
typedef __attribute__((ext_vector_type(4))) float f32x4;

__device__ __forceinline__ float bf2f(short u) {
  union { unsigned int i; float f; } c;
  c.i = ((unsigned int)(unsigned short)u) << 16;
  return c.f;
}

__device__ __forceinline__ void gload_lds16(const void* g, void* lds) {
  __builtin_amdgcn_global_load_lds(
      (__attribute__((address_space(1))) void*)g,
      (__attribute__((address_space(3))) void*)lds, 16, 0, 0);
}

__device__ __forceinline__ int4 pack8(float4 v0, float4 v1) {
  union { __hip_bfloat16 h[8]; int4 v; } u;
  u.h[0] = __float2bfloat16(v0.x); u.h[1] = __float2bfloat16(v0.y);
  u.h[2] = __float2bfloat16(v0.z); u.h[3] = __float2bfloat16(v0.w);
  u.h[4] = __float2bfloat16(v1.x); u.h[5] = __float2bfloat16(v1.y);
  u.h[6] = __float2bfloat16(v1.z); u.h[7] = __float2bfloat16(v1.w);
  return u.v;
}

// ---------------------------------------------------------------------------
// Kernel 1 (prep): R9-proven verbatim + counter zero.
//   blocks [0,2048): cast x->bf16. [2048,2112): W_in->bf16. [2112,2176):
//   transpose-cast W_out -> WoutTb.
// ---------------------------------------------------------------------------
__global__ void __launch_bounds__(256) prep_kernel(
    const float* __restrict__ x, __hip_bfloat16* __restrict__ xb,
    const float* __restrict__ Win, __hip_bfloat16* __restrict__ Winb,
    const float* __restrict__ Wout, __hip_bfloat16* __restrict__ WoutTb,
    unsigned int* __restrict__ ctr) {
  __shared__ __hip_bfloat16 Lds[64][66];
  const int tid = threadIdx.x;
  if (blockIdx.x == 0 && tid == 0) *ctr = 0u;   // reset barrier counter
  if (blockIdx.x < 2048) {
    const int i = blockIdx.x * 256 + tid;
    const float4* xp = (const float4*)x;
    ((int4*)xb)[i] = pack8(xp[2 * i], xp[2 * i + 1]);
    return;
  }
  if (blockIdx.x < 2112) {
    const int e4 = ((blockIdx.x - 2048) * 256 + tid) * 4;
    const float4* wp = (const float4*)Win;
    int4* op = (int4*)Winb;
#pragma unroll
    for (int h = 0; h < 2; ++h)
      op[e4 / 2 + h] = pack8(wp[e4 + 2 * h], wp[e4 + 2 * h + 1]);
    return;
  }
  const int bx = blockIdx.x - 2112;
  const int tr = (bx >> 3) * 64;
  const int tc = (bx & 7) * 64;
#pragma unroll
  for (int it = 0; it < 4; ++it) {
    const int id = it * 256 + tid;
    const int r = id >> 4, c4 = (id & 15) * 4;
    const float4 v = *(const float4*)&Wout[(size_t)(tr + r) * 512 + tc + c4];
    Lds[r][c4]     = __float2bfloat16(v.x);
    Lds[r][c4 + 1] = __float2bfloat16(v.y);
    Lds[r][c4 + 2] = __float2bfloat16(v.z);
    Lds[r][c4 + 3] = __float2bfloat16(v.w);
  }
  __syncthreads();
#pragma unroll
  for (int it = 0; it < 2; ++it) {
    const int id = it * 256 + tid;
    const int j = id >> 3, i0 = (id & 7) * 8;
    union { __hip_bfloat16 h[8]; int4 v; } u;
#pragma unroll
    for (int r = 0; r < 8; ++r) u.h[r] = Lds[i0 + r][j];
    *(int4*)&WoutTb[(size_t)(tc + j) * 512 + tr + i0] = u.v;
  }
}

// ---------------------------------------------------------------------------
// Kernel 2 (fused, 512 blocks x 256 thr, LDS 76KB -> exactly 2 blocks/CU,
// all 512 co-resident):
//   (a) blocks [0,64): one 64x64 WcT tile each (proven R10-0b code);
//       all blocks: gather own 16 rows -> g (proven R9 gather pattern).
//   (b) device-scope atomic barrier (bounded spin; all blocks resident).
//   (c) proven R9 3-deep counted-vmcnt gemm: out = x + g@Wc + b_out.
// ---------------------------------------------------------------------------
__global__ void __launch_bounds__(256, 2) fused_kernel(
    const __hip_bfloat16* __restrict__ Xb,
    const __hip_bfloat16* __restrict__ Winb,
    const __hip_bfloat16* __restrict__ WoutTb,
    __hip_bfloat16* __restrict__ WcT,
    __hip_bfloat16* __restrict__ g,
    const float* __restrict__ x,
    const float* __restrict__ b_out,
    const float* __restrict__ fw,
    const int* __restrict__ routes,
    float* __restrict__ out,
    unsigned int* __restrict__ ctr) {
  union SMem {
    struct { ushort A[3 * 128 * 64]; ushort B[3 * 64 * 64]; } g3;  // 72 KB
    struct { ushort A[64 * 64]; ushort B[64 * 64]; } wc;           // 16 KB
  };
  __shared__ SMem sm;
  __shared__ int   r_s[16][32];
  __shared__ float w_s[16][32];
  const int tid = threadIdx.x;
  const int bid = blockIdx.x;
  const int w = tid >> 6, l = tid & 63;
  const int id2 = (bid & 7) * 64 + (bid >> 3);   // XCD-chunked identity
  const int fr = l & 15, fq = l >> 4;

  // ---- routes/weights for this block's 16 rows (rows id2*16 .. +16) ------
  const int r0 = id2 * 16;
  const int s0 = r0 & (S_LEN - 1);
  const int bb = r0 >> 12;
#pragma unroll
  for (int it = 0; it < 2; ++it) {
    const int idx = it * 256 + tid;   // [0,512)
    r_s[idx >> 5][idx & 31] = routes[(s0 + (idx >> 5)) * K_R + (idx & 31)];
    w_s[idx >> 5][idx & 31] = fw[(s0 + (idx >> 5)) * K_R + (idx & 31)];
  }
  __syncthreads();

  // ---- (a1) wc: blocks [0,64) compute one 64x64 WcT tile (proven code) ---
  if (bid < 64) {
    const int tj = (bid >> 3) * 64, tq = (bid & 7) * 64;
    const int rin = l >> 3, usw = (l & 7) ^ rin;
    const int wr = (w >> 1) * 32, wq = (w & 1) * 32;
    f32x4 acc[2][2] = {};
    for (int k0 = 0; k0 < 512; k0 += 64) {
      __syncthreads();
#pragma unroll
      for (int i = 0; i < 2; ++i) {
        gload_lds16(WoutTb + (size_t)(tj + w * 8 + i * 32 + rin) * 512 + k0 + usw * 8,
                    sm.wc.A + (w * 8 + i * 32) * 64);
        gload_lds16(Winb + (size_t)(tq + w * 8 + i * 32 + rin) * 512 + k0 + usw * 8,
                    sm.wc.B + (w * 8 + i * 32) * 64);
      }
      __syncthreads();
#pragma unroll
      for (int kk = 0; kk < 2; ++kk) {
        const int u = (kk * 4 + fq) ^ (fr & 7);
        bf16x8 af[2], bfv[2];
#pragma unroll
        for (int m = 0; m < 2; ++m)
          af[m] = *(const bf16x8*)(sm.wc.A + (wr + m * 16 + fr) * 64 + u * 8);
#pragma unroll
        for (int n = 0; n < 2; ++n)
          bfv[n] = *(const bf16x8*)(sm.wc.B + (wq + n * 16 + fr) * 64 + u * 8);
#pragma unroll
        for (int m = 0; m < 2; ++m)
#pragma unroll
          for (int n = 0; n < 2; ++n)
            acc[m][n] = __builtin_amdgcn_mfma_f32_16x16x32_bf16(af[m], bfv[n], acc[m][n], 0, 0, 0);
      }
    }
#pragma unroll
    for (int m = 0; m < 2; ++m)
#pragma unroll
      for (int n = 0; n < 2; ++n)
#pragma unroll
        for (int r = 0; r < 4; ++r)
          WcT[(size_t)(tj + wr + m * 16 + fq * 4 + r) * 512 + tq + wq + n * 16 + fr] =
              __float2bfloat16(acc[m][n][r]);
    __syncthreads();   // sm.wc reads done before gemm phase reuses union
  }

  // ---- (a2) gather 16 rows (proven R9 pattern, 4 rows/wave x 4 rounds) ---
  {
    const __hip_bfloat16* xbb = Xb + (size_t)bb * S_LEN * D_DIM + l * 8;
#pragma unroll
    for (int rr = 0; rr < 4; ++rr) {
      const int rl = w * 4 + rr;
      const int row = r0 + rl;
      float acc[8] = {};
#pragma unroll 8
      for (int k = 0; k < K_R; ++k) {
        const float wk = w_s[rl][k];
        const bf16x8 v = *(const bf16x8*)(xbb + (size_t)r_s[rl][k] * D_DIM);
#pragma unroll
        for (int j = 0; j < 8; ++j) acc[j] = fmaf(wk, bf2f(v[j]), acc[j]);
      }
      union { __hip_bfloat16 h[8]; int4 v; } u;
#pragma unroll
      for (int j = 0; j < 8; ++j) u.h[j] = __float2bfloat16(acc[j]);
      *(int4*)(g + (size_t)row * D_DIM + l * 8) = u.v;
    }
  }

  // ---- (b) device-scope barrier: all 512 blocks co-resident (2/CU) -------
  __threadfence();          // release: g + WcT visible device-wide
  __syncthreads();
  if (tid == 0) {
    atomicAdd(ctr, 1u);
    int guard = 0;
    while (atomicAdd(ctr, 0u) < 512u && guard < (1 << 28)) {
      ++guard;
      __builtin_amdgcn_s_sleep(2);
    }
  }
  __syncthreads();
  __threadfence();          // acquire

  // ---- (c) gemm: out = x + g @ Wc + b_out  (proven R9 3-deep pipeline) ---
  {
    const int bm0 = (id2 >> 3) * 128;
    const int bn0 = (id2 & 7) * 64;
    const int wr  = (w >> 1) * 64;
    const int wcn = (w & 1) * 32;
    const int rin = l >> 3;
    const int usw = (l & 7) ^ rin;
    const __hip_bfloat16* gA = g + (size_t)(bm0 + w * 8 + rin) * D_DIM + usw * 8;
    const __hip_bfloat16* gB = WcT + (size_t)(bn0 + w * 8 + rin) * D_DIM + usw * 8;
    ushort* AsU = sm.g3.A;
    ushort* BsU = sm.g3.B;
    f32x4 acc[4][2] = {};

#define STAGE(buf, k0)                                                          \
  {                                                                             \
    _Pragma("unroll")                                                           \
    for (int i = 0; i < 4; ++i)                                                 \
      gload_lds16(gA + (size_t)(i * 32) * D_DIM + (k0),                         \
                  AsU + (buf) * 8192 + (w * 8 + i * 32) * 64);                  \
    _Pragma("unroll")                                                           \
    for (int j = 0; j < 2; ++j)                                                 \
      gload_lds16(gB + (size_t)(j * 32) * D_DIM + (k0),                         \
                  BsU + (buf) * 4096 + (w * 8 + j * 32) * 64);                  \
  }

#define COMPUTE(buf)                                                            \
  {                                                                             \
    _Pragma("unroll")                                                           \
    for (int kk = 0; kk < 2; ++kk) {                                            \
      const int u = (kk * 4 + fq) ^ (fr & 7);                                   \
      bf16x8 af[4], bfv[2];                                                     \
      _Pragma("unroll")                                                         \
      for (int m = 0; m < 4; ++m)                                               \
        af[m] = *(const bf16x8*)(AsU + (buf) * 8192 + (wr + m * 16 + fr) * 64 + u * 8); \
      _Pragma("unroll")                                                         \
      for (int n = 0; n < 2; ++n)                                               \
        bfv[n] = *(const bf16x8*)(BsU + (buf) * 4096 + (wcn + n * 16 + fr) * 64 + u * 8); \
      _Pragma("unroll")                                                         \
      for (int m = 0; m < 4; ++m)                                               \
        _Pragma("unroll")                                                       \
        for (int n = 0; n < 2; ++n)                                             \
          acc[m][n] = __builtin_amdgcn_mfma_f32_16x16x32_bf16(                  \
              af[m], bfv[n], acc[m][n], 0, 0, 0);                               \
    }                                                                           \
  }

    STAGE(0, 0);
    STAGE(1, 64);
#pragma unroll
    for (int t = 0; t < 7; ++t) {
      asm volatile("s_waitcnt vmcnt(6)" ::: "memory");
      __builtin_amdgcn_s_barrier();
      __builtin_amdgcn_sched_barrier(0);
      if (t < 6) STAGE((t + 2) % 3, (t + 2) * 64);
      COMPUTE(t % 3);
    }
    asm volatile("s_waitcnt vmcnt(0)" ::: "memory");
    __builtin_amdgcn_s_barrier();
    __builtin_amdgcn_sched_barrier(0);
    COMPUTE(1);   // 7 % 3
#undef STAGE
#undef COMPUTE

    const float bb0 = b_out[bn0 + wcn + fr];
    const float bb1 = b_out[bn0 + wcn + 16 + fr];
#pragma unroll
    for (int m = 0; m < 4; ++m)
#pragma unroll
      for (int r = 0; r < 4; ++r) {
        const int grow = bm0 + wr + m * 16 + fq * 4 + r;
        const size_t base = (size_t)grow * D_DIM + bn0 + wcn + fr;
        out[base]      = acc[m][0][r] + x[base]      + bb0;
        out[base + 16] = acc[m][1][r] + x[base + 16] + bb1;
      }
  }
}

// ---------------------------------------------------------------------------
extern "C" void kernel_launch(void* const* d_in, const int* in_sizes, int n_in,
                              void* d_out, int out_size, void* d_ws, size_t ws_size,
                              hipStream_t stream) {
  const float* x      = (const float*)d_in[0];
  const float* W_in   = (const float*)d_in[1];
  const float* W_out  = (const float*)d_in[2];
  const float* b_out  = (const float*)d_in[3];
  const float* fw     = (const float*)d_in[4];
  const int*   routes = (const int*)d_in[5];
  float* out = (float*)d_out;

  // workspace: Xb(8MB) | WcT(512KB) | g(8MB) | Winb(512KB) | WoutTb(512KB) | ctr
  char* ws = (char*)d_ws;
  __hip_bfloat16* Xb     = (__hip_bfloat16*)ws;
  __hip_bfloat16* WcT    = (__hip_bfloat16*)(ws + 8388608);
  __hip_bfloat16* g      = (__hip_bfloat16*)(ws + 8912896);
  __hip_bfloat16* Winb   = (__hip_bfloat16*)(ws + 17301504);
  __hip_bfloat16* WoutTb = (__hip_bfloat16*)(ws + 17825792);
  unsigned int*   ctr    = (unsigned int*)(ws + 20971520);

  // 1) casts + transpose + barrier-counter reset (R9-proven)
  prep_kernel<<<2176, 256, 0, stream>>>(x, Xb, W_in, Winb, W_out, WoutTb, ctr);
  // 2) fused: wc || gather -> device barrier -> gemm+epilogue
  fused_kernel<<<512, 256, 0, stream>>>(Xb, Winb, WoutTb, WcT, g, x, b_out,
                                        fw, routes, out, ctr);
}

// Round 12
// 35.383 us; speedup vs baseline: 5.0976x; 4.1226x over previous
//
#include <hip/hip_runtime.h>
#include <hip/hip_bf16.h>
#include <stdint.h>

// Problem constants (B,S,D,K) = (2,4096,512,32)
#define S_LEN  4096
#define D_DIM  512
#define K_R    32
#define M_ROWS 8192

typedef __attribute__((ext_vector_type(8))) short bf16x8;
typedef __attribute__((ext_vector_type(4))) float f32x4;

__device__ __forceinline__ float bf2f(short u) {
  union { unsigned int i; float f; } c;
  c.i = ((unsigned int)(unsigned short)u) << 16;
  return c.f;
}

__device__ __forceinline__ void gload_lds16(const void* g, void* lds) {
  __builtin_amdgcn_global_load_lds(
      (__attribute__((address_space(1))) void*)g,
      (__attribute__((address_space(3))) void*)lds, 16, 0, 0);
}

__device__ __forceinline__ int4 pack8(float4 v0, float4 v1) {
  union { __hip_bfloat16 h[8]; int4 v; } u;
  u.h[0] = __float2bfloat16(v0.x); u.h[1] = __float2bfloat16(v0.y);
  u.h[2] = __float2bfloat16(v0.z); u.h[3] = __float2bfloat16(v0.w);
  u.h[4] = __float2bfloat16(v1.x); u.h[5] = __float2bfloat16(v1.y);
  u.h[6] = __float2bfloat16(v1.z); u.h[7] = __float2bfloat16(v1.w);
  return u.v;
}

// ---------------------------------------------------------------------------
// Kernel 1 (prep): R9-proven verbatim.
//   blocks [0,2048): cast x->bf16. [2048,2112): W_in->bf16. [2112,2176):
//   transpose-cast W_out -> WoutTb.
// ---------------------------------------------------------------------------
__global__ void __launch_bounds__(256) prep_kernel(
    const float* __restrict__ x, __hip_bfloat16* __restrict__ xb,
    const float* __restrict__ Win, __hip_bfloat16* __restrict__ Winb,
    const float* __restrict__ Wout, __hip_bfloat16* __restrict__ WoutTb) {
  __shared__ __hip_bfloat16 Lds[64][66];
  const int tid = threadIdx.x;
  if (blockIdx.x < 2048) {
    const int i = blockIdx.x * 256 + tid;
    const float4* xp = (const float4*)x;
    ((int4*)xb)[i] = pack8(xp[2 * i], xp[2 * i + 1]);
    return;
  }
  if (blockIdx.x < 2112) {
    const int e4 = ((blockIdx.x - 2048) * 256 + tid) * 4;
    const float4* wp = (const float4*)Win;
    int4* op = (int4*)Winb;
#pragma unroll
    for (int h = 0; h < 2; ++h)
      op[e4 / 2 + h] = pack8(wp[e4 + 2 * h], wp[e4 + 2 * h + 1]);
    return;
  }
  const int bx = blockIdx.x - 2112;
  const int tr = (bx >> 3) * 64;
  const int tc = (bx & 7) * 64;
#pragma unroll
  for (int it = 0; it < 4; ++it) {
    const int id = it * 256 + tid;
    const int r = id >> 4, c4 = (id & 15) * 4;
    const float4 v = *(const float4*)&Wout[(size_t)(tr + r) * 512 + tc + c4];
    Lds[r][c4]     = __float2bfloat16(v.x);
    Lds[r][c4 + 1] = __float2bfloat16(v.y);
    Lds[r][c4 + 2] = __float2bfloat16(v.z);
    Lds[r][c4 + 3] = __float2bfloat16(v.w);
  }
  __syncthreads();
#pragma unroll
  for (int it = 0; it < 2; ++it) {
    const int id = it * 256 + tid;
    const int j = id >> 3, i0 = (id & 7) * 8;
    union { __hip_bfloat16 h[8]; int4 v; } u;
#pragma unroll
    for (int r = 0; r < 8; ++r) u.h[r] = Lds[i0 + r][j];
    *(int4*)&WoutTb[(size_t)(tc + j) * 512 + tr + i0] = u.v;
  }
}

// ---------------------------------------------------------------------------
// Kernel 2 (mid): R9-proven verbatim.
//   blocks [0,32): wcgemm WcT = WoutTb x Winb (runs first, hides under gather)
//   blocks [32,2080): gather g[row,:] = sum_k w[s,k]*Xb[b,route,:]
// ---------------------------------------------------------------------------
#define BM 128
#define BN 64
#define BK 64

__global__ void __launch_bounds__(256) mid_kernel(
    const __hip_bfloat16* __restrict__ xb,
    const float* __restrict__ fw,
    const int* __restrict__ routes,
    __hip_bfloat16* __restrict__ g,
    const __hip_bfloat16* __restrict__ WoutTb,   // A  (m=j, k=p)
    const __hip_bfloat16* __restrict__ Winb,     // BT (n=q, k=p)
    __hip_bfloat16* __restrict__ WcT) {
  __shared__ __hip_bfloat16 As[BM][BK];   // 16 KB
  __shared__ __hip_bfloat16 Bs[BN][BK];   //  8 KB
  __shared__ float w_s[4][K_R];
  __shared__ int   r_s[4][K_R];
  const int tid = threadIdx.x;
  const int w = tid >> 6, l = tid & 63;

  if (blockIdx.x >= 32) {
    // ---- gather path ----
    const int lin = blockIdx.x - 32;
    const int bchunk = (lin & 7) * 256 + (lin >> 3); // XCD-contiguous rows
    const int row = bchunk * 4 + w;
    const int s = row & (S_LEN - 1);
    const int b = row >> 12;
    if (l < K_R) {
      r_s[w][l] = routes[s * K_R + l];
      w_s[w][l] = fw[s * K_R + l];
    }
    __syncthreads();
    const __hip_bfloat16* xbb = xb + (size_t)b * S_LEN * D_DIM + l * 8;
    float acc[8] = {};
#pragma unroll 8
    for (int k = 0; k < K_R; ++k) {
      const float wk = w_s[w][k];
      const bf16x8 v = *(const bf16x8*)(xbb + (size_t)r_s[w][k] * D_DIM);
#pragma unroll
      for (int j = 0; j < 8; ++j) acc[j] = fmaf(wk, bf2f(v[j]), acc[j]);
    }
    union { __hip_bfloat16 h[8]; int4 v; } u;
#pragma unroll
    for (int j = 0; j < 8; ++j) u.h[j] = __float2bfloat16(acc[j]);
    *(int4*)(g + (size_t)row * D_DIM + l * 8) = u.v;
    return;
  }

  // ---- wcgemm path: WcT[j][q] = sum_p WoutTb[j][p] * Winb[q][p] ----
  const int id2 = blockIdx.x;           // [0,32)
  const int bm0 = (id2 >> 3) * BM;
  const int bn0 = (id2 & 7) * BN;
  const int wr  = (w >> 1) * 64;
  const int wcn = (w & 1) * 32;

  const int rin = l >> 3;
  const int usw = (l & 7) ^ rin;
  const __hip_bfloat16* gA = WoutTb + (size_t)(bm0 + w * 8 + rin) * D_DIM + usw * 8;
  const __hip_bfloat16* gB = Winb   + (size_t)(bn0 + w * 8 + rin) * D_DIM + usw * 8;
  __hip_bfloat16* ldsA = &As[w * 8][0];
  __hip_bfloat16* ldsB = &Bs[w * 8][0];
  const int fr = l & 15, fq = l >> 4;

  f32x4 acc[4][2] = {};
  for (int k0 = 0; k0 < D_DIM; k0 += BK) {
#pragma unroll
    for (int i = 0; i < 4; ++i)
      gload_lds16(gA + (size_t)(i * 32) * D_DIM + k0, ldsA + i * 32 * BK);
#pragma unroll
    for (int j = 0; j < 2; ++j)
      gload_lds16(gB + (size_t)(j * 32) * D_DIM + k0, ldsB + j * 32 * BK);
    __syncthreads();
#pragma unroll
    for (int kk = 0; kk < 2; ++kk) {
      const int u = (kk * 4 + fq) ^ (fr & 7);
      bf16x8 af[4], bfv[2];
#pragma unroll
      for (int m = 0; m < 4; ++m)
        af[m] = *(const bf16x8*)&As[wr + m * 16 + fr][u * 8];
#pragma unroll
      for (int n = 0; n < 2; ++n)
        bfv[n] = *(const bf16x8*)&Bs[wcn + n * 16 + fr][u * 8];
#pragma unroll
      for (int m = 0; m < 4; ++m)
#pragma unroll
        for (int n = 0; n < 2; ++n)
          acc[m][n] = __builtin_amdgcn_mfma_f32_16x16x32_bf16(af[m], bfv[n], acc[m][n], 0, 0, 0);
    }
    __syncthreads();
  }
#pragma unroll
  for (int m = 0; m < 4; ++m)
#pragma unroll
    for (int n = 0; n < 2; ++n)
#pragma unroll
      for (int r = 0; r < 4; ++r) {
        const int grow = bm0 + wr + m * 16 + fq * 4 + r;
        const int gcol = bn0 + wcn + n * 16 + fr;
        WcT[(size_t)grow * D_DIM + gcol] = __float2bfloat16(acc[m][n][r]);
      }
}

// ---------------------------------------------------------------------------
// Kernel 3: out = x + g @ Wc + b_out   (M=8192, N=512, K=512)
//   128x128 tile, 512 threads (8 waves, each 64x32 output), BK=64,
//   2-deep counted-vmcnt pipeline: STAGE(t+1) issued, s_waitcnt vmcnt(4)
//   (next tile's 4 loads stay in flight across the barrier), compute, barrier.
//   B-panel L2 re-read: 256MB (BN=64) -> 32MB (BN=128).
// ---------------------------------------------------------------------------
#define GBN 128

__global__ void __launch_bounds__(512, 4) gemm_out_kernel(
    const __hip_bfloat16* __restrict__ A,    // g (M x 512)
    const __hip_bfloat16* __restrict__ BT,   // WcT (n x k)
    const float* __restrict__ x,
    const float* __restrict__ b_out,
    float* __restrict__ out) {
  __shared__ __hip_bfloat16 As[2][BM][BK];    // 32 KB
  __shared__ __hip_bfloat16 Bs[2][GBN][BK];   // 32 KB  (64 KB -> 2 blocks/CU)
  const int tid = threadIdx.x;
  const int w = tid >> 6, l = tid & 63;

  // XCD-chunked: 256 blocks = 8 XCDs x 32; m-tiles match gather's row chunks.
  const int bid = blockIdx.x;
  const int id2 = (bid & 7) * 32 + (bid >> 3);
  const int bm0 = (id2 >> 2) * BM;     // 64 m-tiles
  const int bn0 = (id2 & 3) * GBN;     // 4 n-tiles

  const int wr  = (w >> 2) * 64;       // wave row (2 m-halves)
  const int wcn = (w & 3) * 32;        // wave col (4 n-quarters)

  // staging: wave w owns 16 rows of A and 16 rows of B (2 gloads each).
  const int rin = l >> 3;
  const int usw = (l & 7) ^ rin;
  const __hip_bfloat16* gA = A + (size_t)(bm0 + w * 16 + rin) * D_DIM + usw * 8;
  const __hip_bfloat16* gB = BT + (size_t)(bn0 + w * 16 + rin) * D_DIM + usw * 8;

  const int fr = l & 15, fq = l >> 4;
  f32x4 acc[4][2] = {};

#define STAGE(buf, k0)                                                          \
  {                                                                             \
    _Pragma("unroll")                                                           \
    for (int i = 0; i < 2; ++i)                                                 \
      gload_lds16(gA + (size_t)(i * 8) * D_DIM + (k0),                          \
                  &As[buf][w * 16 + i * 8][0]);                                 \
    _Pragma("unroll")                                                           \
    for (int j = 0; j < 2; ++j)                                                 \
      gload_lds16(gB + (size_t)(j * 8) * D_DIM + (k0),                          \
                  &Bs[buf][w * 16 + j * 8][0]);                                 \
  }

#define COMPUTE(buf)                                                            \
  {                                                                             \
    _Pragma("unroll")                                                           \
    for (int kk = 0; kk < 2; ++kk) {                                            \
      const int u = (kk * 4 + fq) ^ (fr & 7);                                   \
      bf16x8 af[4], bfv[2];                                                     \
      _Pragma("unroll")                                                         \
      for (int m = 0; m < 4; ++m)                                               \
        af[m] = *(const bf16x8*)&As[buf][wr + m * 16 + fr][u * 8];              \
      _Pragma("unroll")                                                         \
      for (int n = 0; n < 2; ++n)                                               \
        bfv[n] = *(const bf16x8*)&Bs[buf][wcn + n * 16 + fr][u * 8];            \
      _Pragma("unroll")                                                         \
      for (int m = 0; m < 4; ++m)                                               \
        _Pragma("unroll")                                                       \
        for (int n = 0; n < 2; ++n)                                             \
          acc[m][n] = __builtin_amdgcn_mfma_f32_16x16x32_bf16(                  \
              af[m], bfv[n], acc[m][n], 0, 0, 0);                               \
    }                                                                           \
  }

  STAGE(0, 0);
#pragma unroll
  for (int t = 0; t < 7; ++t) {
    STAGE((t + 1) & 1, (t + 1) * BK);           // issue next tile's 4 loads
    asm volatile("s_waitcnt vmcnt(4)" ::: "memory");  // tile t's loads done
    __builtin_amdgcn_s_barrier();
    __builtin_amdgcn_sched_barrier(0);
    COMPUTE(t & 1);
    __builtin_amdgcn_s_barrier();               // readers done before overwrite
  }
  asm volatile("s_waitcnt vmcnt(0)" ::: "memory");
  __builtin_amdgcn_s_barrier();
  __builtin_amdgcn_sched_barrier(0);
  COMPUTE(1);                                   // tile 7
#undef STAGE
#undef COMPUTE

  const float bb0 = b_out[bn0 + wcn + fr];
  const float bb1 = b_out[bn0 + wcn + 16 + fr];
#pragma unroll
  for (int m = 0; m < 4; ++m)
#pragma unroll
    for (int r = 0; r < 4; ++r) {
      const int grow = bm0 + wr + m * 16 + fq * 4 + r;
      const size_t base = (size_t)grow * D_DIM + bn0 + wcn + fr;
      out[base]      = acc[m][0][r] + x[base]      + bb0;
      out[base + 16] = acc[m][1][r] + x[base + 16] + bb1;
    }
}

// ---------------------------------------------------------------------------
extern "C" void kernel_launch(void* const* d_in, const int* in_sizes, int n_in,
                              void* d_out, int out_size, void* d_ws, size_t ws_size,
                              hipStream_t stream) {
  const float* x      = (const float*)d_in[0];
  const float* W_in   = (const float*)d_in[1];
  const float* W_out  = (const float*)d_in[2];
  const float* b_out  = (const float*)d_in[3];
  const float* fw     = (const float*)d_in[4];
  const int*   routes = (const int*)d_in[5];
  float* out = (float*)d_out;

  // workspace: Xb(8MB) | WcT(512KB) | g(8MB) | Winb(512KB) | WoutTb(512KB)
  char* ws = (char*)d_ws;
  __hip_bfloat16* Xb     = (__hip_bfloat16*)ws;
  __hip_bfloat16* WcT    = (__hip_bfloat16*)(ws + 8388608);
  __hip_bfloat16* g      = (__hip_bfloat16*)(ws + 8912896);
  __hip_bfloat16* Winb   = (__hip_bfloat16*)(ws + 17301504);
  __hip_bfloat16* WoutTb = (__hip_bfloat16*)(ws + 17825792);

  // 1) casts + transpose (R9-proven)
  prep_kernel<<<2176, 256, 0, stream>>>(x, Xb, W_in, Winb, W_out, WoutTb);
  // 2) wcgemm (32 blocks, first) || gather (2048 blocks)  (R9-proven)
  mid_kernel<<<2080, 256, 0, stream>>>(Xb, fw, routes, g, WoutTb, Winb, WcT);
  // 3) out = x + g @ Wc + b_out  (128x128 tile, 2-deep counted-vmcnt)
  gemm_out_kernel<<<256, 512, 0, stream>>>(g, WcT, x, b_out, out);
}